// Round 1
// baseline (2094.783 us; speedup 1.0000x reference)
//
#include <hip/hip_runtime.h>
#include <cstdint>
#include <cstddef>

#define BB 4
#define NN 8192
#define MM 2048
#define KK 16
#define DP 128
#define DM 256

// ---------------------------------------------------------------------------
// Kernel 1: exact KNN (k=16) per query. One 256-thread workgroup per query.
// dist = |q|^2 + |x|^2 - 2 q.x computed in f32 like the reference.
// Selection: 16 serial argmin rounds over sortable (dist,idx) keys so ties
// break toward the lower index (matches jax.lax.top_k stability).
// ---------------------------------------------------------------------------
__global__ __launch_bounds__(256) void knn_kernel(
    const float* __restrict__ xyz, const float* __restrict__ query,
    int* __restrict__ knn_out)
{
  __shared__ unsigned keys[NN];          // sortable f32 distance bits
  __shared__ unsigned long long red[4];  // per-wave reduce scratch
  const int tid = threadIdx.x;
  const int bm  = blockIdx.x;
  const int b   = bm >> 11;              // M = 2048
  const float* q = query + (size_t)bm * 131;
  const float qx = q[0], qy = q[1], qz = q[2];
  const float q2 = qx*qx + qy*qy + qz*qz;
  const float* X = xyz + (size_t)b * NN * 3;

  for (int n = tid; n < NN; n += 256) {
    float xx = X[3*n + 0], xy = X[3*n + 1], xz = X[3*n + 2];
    float x2 = xx*xx + xy*xy + xz*xz;
    float cr = qx*xx + qy*xy + qz*xz;
    float d  = q2 + x2 - 2.0f * cr;
    unsigned u = __float_as_uint(d);
    u = (u & 0x80000000u) ? ~u : (u | 0x80000000u);  // ascending-sortable
    keys[n] = u;
  }
  __syncthreads();

  for (int r = 0; r < KK; ++r) {
    unsigned long long best = ~0ull;
    for (int n = tid; n < NN; n += 256) {
      unsigned long long cand = ((unsigned long long)keys[n] << 32) | (unsigned)n;
      best = cand < best ? cand : best;
    }
    #pragma unroll
    for (int d = 32; d >= 1; d >>= 1) {
      unsigned long long o = __shfl_xor(best, d, 64);
      best = o < best ? o : best;
    }
    if ((tid & 63) == 0) red[tid >> 6] = best;
    __syncthreads();
    if (tid == 0) {
      unsigned long long w01 = red[0] < red[1] ? red[0] : red[1];
      unsigned long long w23 = red[2] < red[3] ? red[2] : red[3];
      unsigned long long w   = w01 < w23 ? w01 : w23;
      unsigned n = (unsigned)(w & 0xffffffffu);
      keys[n] = 0xFFFFFFFFu;             // remove winner
      knn_out[bm*KK + r] = (int)n;
    }
    __syncthreads();
  }
}

// load 16 contiguous floats from LDS (64B-aligned) as 4x float4
__device__ __forceinline__ void load16(const float* __restrict__ p, float* v) {
  const float4* q = (const float4*)p;
  float4 a = q[0], b = q[1], c = q[2], d = q[3];
  v[0]=a.x; v[1]=a.y; v[2]=a.z; v[3]=a.w;
  v[4]=b.x; v[5]=b.y; v[6]=b.z; v[7]=b.w;
  v[8]=c.x; v[9]=c.y; v[10]=c.z; v[11]=c.w;
  v[12]=d.x; v[13]=d.y; v[14]=d.z; v[15]=d.w;
}

// ---------------------------------------------------------------------------
// Kernel 2: fully fused per-query transformer block. One 256-thread WG per
// query; thread j owns output channel j (0..255) of every D_MODEL-wide stage.
// All 16x256 intermediates live in LDS transposed as [channel][neighbor]
// (contiguous in the 16 neighbors -> 4x ds_read_b128 broadcast per K-step).
// pe, v+pe, q_j, logits, softmax stay in registers (purely elementwise use).
// ---------------------------------------------------------------------------
__global__ __launch_bounds__(256) void fused_kernel(
    const float* __restrict__ xyz, const float* __restrict__ features,
    const float* __restrict__ query,
    const float* __restrict__ fc1_w, const float* __restrict__ fc1_b,
    const float* __restrict__ fc2_w, const float* __restrict__ fc2_b,
    const float* __restrict__ d1_w,  const float* __restrict__ d1_b,
    const float* __restrict__ d2_w,  const float* __restrict__ d2_b,
    const float* __restrict__ g1_w,  const float* __restrict__ g1_b,
    const float* __restrict__ g2_w,  const float* __restrict__ g2_b,
    const float* __restrict__ wq,    const float* __restrict__ wk,
    const float* __restrict__ wv,
    const int* __restrict__ knn_idx,
    float* __restrict__ out_res, float* __restrict__ out_attn)
{
  __shared__ alignas(16) float s_qf[DP];         // query features
  __shared__ alignas(16) float s_knnfT[DP*KK];   // gathered features [i][r]
  __shared__ alignas(16) float s_xT[DM*KK];      // x, later a  [i][r]
  __shared__ alignas(16) float s_hT[DM*KK];      // h1, later h [i][r]
  __shared__ float s_delta[KK*4];                // [r][xyz,pad]
  __shared__ int   s_idx[KK];
  __shared__ float s_rm[DM];                     // res_model

  const int tid = threadIdx.x;
  const int bm  = blockIdx.x;
  const int b   = bm >> 11;                      // M = 2048
  const float* qrow = query + (size_t)bm * 131;

  if (tid < KK) s_idx[tid] = knn_idx[bm*KK + tid];
  if (tid >= 64 && tid < 64 + DP) s_qf[tid - 64] = qrow[3 + (tid - 64)];
  __syncthreads();
  if (tid < KK) {
    const float* p = xyz + ((size_t)b*NN + s_idx[tid]) * 3;
    s_delta[tid*4 + 0] = qrow[0] - p[0];
    s_delta[tid*4 + 1] = qrow[1] - p[1];
    s_delta[tid*4 + 2] = qrow[2] - p[2];
  }
  for (int e = tid; e < KK*DP; e += 256) {
    int r = e >> 7, i = e & (DP - 1);
    s_knnfT[i*KK + r] = features[((size_t)b*NN + s_idx[r])*DP + i];
  }
  __syncthreads();

  const int j = tid;   // output channel

  // q_j = (query_f @ wq)[j]
  float q_j = 0.f;
  #pragma unroll 4
  for (int i = 0; i < DP; ++i) q_j = fmaf(s_qf[i], wq[i*DM + j], q_j);

  // x = knn_f @ fc1_w + fc1_b   -> s_xT
  float acc[16];
  {
    float bb = fc1_b[j];
    #pragma unroll
    for (int r = 0; r < 16; ++r) acc[r] = bb;
    #pragma unroll 2
    for (int i = 0; i < DP; ++i) {
      float w = fc1_w[i*DM + j];
      float xv[16]; load16(&s_knnfT[i*KK], xv);
      #pragma unroll
      for (int r = 0; r < 16; ++r) acc[r] = fmaf(xv[r], w, acc[r]);
    }
    #pragma unroll
    for (int r = 0; r < 16; ++r) s_xT[j*16 + r] = acc[r];
  }

  // h1 = relu(delta @ d1_w + d1_b) -> s_hT
  {
    float w0 = d1_w[j], w1 = d1_w[DM + j], w2 = d1_w[2*DM + j], bb = d1_b[j];
    #pragma unroll
    for (int r = 0; r < 16; ++r) {
      float v = fmaf(s_delta[r*4+2], w2,
                fmaf(s_delta[r*4+1], w1,
                fmaf(s_delta[r*4+0], w0, bb)));
      s_hT[j*16 + r] = v > 0.f ? v : 0.f;
    }
  }
  __syncthreads();   // s_xT (x), s_hT (h1) visible

  // pe = h1 @ d2_w + d2_b   (registers)
  float pe[16];
  {
    float bb = d2_b[j];
    #pragma unroll
    for (int r = 0; r < 16; ++r) pe[r] = bb;
    #pragma unroll 2
    for (int i = 0; i < DM; ++i) {
      float w = d2_w[i*DM + j];
      float hv[16]; load16(&s_hT[i*16], hv);
      #pragma unroll
      for (int r = 0; r < 16; ++r) pe[r] = fmaf(hv[r], w, pe[r]);
    }
  }

  // k = x @ wk, v = x @ wv  (one pass over x)
  float ak[16], av[16];
  {
    #pragma unroll
    for (int r = 0; r < 16; ++r) { ak[r] = 0.f; av[r] = 0.f; }
    #pragma unroll 2
    for (int i = 0; i < DM; ++i) {
      float wkw = wk[i*DM + j];
      float wvw = wv[i*DM + j];
      float xv[16]; load16(&s_xT[i*16], xv);
      #pragma unroll
      for (int r = 0; r < 16; ++r) {
        ak[r] = fmaf(xv[r], wkw, ak[r]);
        av[r] = fmaf(xv[r], wvw, av[r]);
      }
    }
  }
  float vpe[16];
  #pragma unroll
  for (int r = 0; r < 16; ++r) vpe[r] = av[r] + pe[r];

  __syncthreads();   // everyone done reading s_xT / s_hT
  #pragma unroll
  for (int r = 0; r < 16; ++r) s_xT[j*16 + r] = q_j - ak[r] + pe[r];  // a
  __syncthreads();

  // h = relu(a @ g1_w + g1_b)
  {
    float bb = g1_b[j];
    #pragma unroll
    for (int r = 0; r < 16; ++r) acc[r] = bb;
    #pragma unroll 2
    for (int i = 0; i < DM; ++i) {
      float w = g1_w[i*DM + j];
      float avv[16]; load16(&s_xT[i*16], avv);
      #pragma unroll
      for (int r = 0; r < 16; ++r) acc[r] = fmaf(avv[r], w, acc[r]);
    }
  }
  #pragma unroll
  for (int r = 0; r < 16; ++r) s_hT[j*16 + r] = acc[r] > 0.f ? acc[r] : 0.f;
  __syncthreads();

  // logits = h @ g2_w + g2_b
  float lg[16];
  {
    float bb = g2_b[j];
    #pragma unroll
    for (int r = 0; r < 16; ++r) lg[r] = bb;
    #pragma unroll 2
    for (int i = 0; i < DM; ++i) {
      float w = g2_w[i*DM + j];
      float hv[16]; load16(&s_hT[i*16], hv);
      #pragma unroll
      for (int r = 0; r < 16; ++r) lg[r] = fmaf(hv[r], w, lg[r]);
    }
  }

  // softmax over the 16 neighbors (axis=-2), scale 1/sqrt(256)=1/16
  float mx = -INFINITY;
  #pragma unroll
  for (int r = 0; r < 16; ++r) { lg[r] *= 0.0625f; mx = lg[r] > mx ? lg[r] : mx; }
  float ssum = 0.f;
  #pragma unroll
  for (int r = 0; r < 16; ++r) { lg[r] = __expf(lg[r] - mx); ssum += lg[r]; }
  float inv = 1.0f / ssum;

  float rm = 0.f;
  float* oat = out_attn + (size_t)bm * (KK*DM) + j;
  #pragma unroll
  for (int r = 0; r < 16; ++r) {
    float at = lg[r] * inv;
    oat[r*DM] = at;                      // attn output, coalesced over j
    rm = fmaf(at, vpe[r], rm);
  }
  s_rm[j] = rm;
  __syncthreads();

  // res = res_model @ fc2_w + fc2_b + query_f
  if (j < DP) {
    float o = fc2_b[j] + s_qf[j];
    #pragma unroll 4
    for (int i = 0; i < DM; ++i) o = fmaf(s_rm[i], fc2_w[i*DP + j], o);
    out_res[(size_t)bm*DP + j] = o;
  }
}

extern "C" void kernel_launch(void* const* d_in, const int* in_sizes, int n_in,
                              void* d_out, int out_size, void* d_ws, size_t ws_size,
                              hipStream_t stream) {
  const float* xyz      = (const float*)d_in[0];
  const float* features = (const float*)d_in[1];
  const float* query    = (const float*)d_in[2];
  const float* fc1_w    = (const float*)d_in[3];
  const float* fc1_b    = (const float*)d_in[4];
  const float* fc2_w    = (const float*)d_in[5];
  const float* fc2_b    = (const float*)d_in[6];
  const float* d1_w     = (const float*)d_in[7];
  const float* d1_b     = (const float*)d_in[8];
  const float* d2_w     = (const float*)d_in[9];
  const float* d2_b     = (const float*)d_in[10];
  const float* g1_w     = (const float*)d_in[11];
  const float* g1_b     = (const float*)d_in[12];
  const float* g2_w     = (const float*)d_in[13];
  const float* g2_b     = (const float*)d_in[14];
  const float* wq       = (const float*)d_in[15];
  const float* wk       = (const float*)d_in[16];
  const float* wv       = (const float*)d_in[17];

  int* knn = (int*)d_ws;                               // B*M*16 ints
  float* out_res  = (float*)d_out;                     // B*M*128
  float* out_attn = (float*)d_out + (size_t)BB*MM*DP;  // B*M*16*256

  knn_kernel<<<BB*MM, 256, 0, stream>>>(xyz, query, knn);
  fused_kernel<<<BB*MM, 256, 0, stream>>>(
      xyz, features, query, fc1_w, fc1_b, fc2_w, fc2_b,
      d1_w, d1_b, d2_w, d2_b, g1_w, g1_b, g2_w, g2_b,
      wq, wk, wv, knn, out_res, out_attn);
}

// Round 2
// 837.749 us; speedup vs baseline: 2.5005x; 2.5005x over previous
//
#include <hip/hip_runtime.h>
#include <cstdint>
#include <cstddef>

#define BB 4
#define NN 8192
#define MM 2048
#define KK 16
#define DP 128
#define DM 256
#define QROW 131  // 3 + 128 floats per query row

typedef __attribute__((ext_vector_type(8))) short short8;
typedef __attribute__((ext_vector_type(4))) float floatx4;

__device__ __forceinline__ unsigned short f2bf(float x) {
  unsigned u = __float_as_uint(x);
  unsigned r = (u + 0x7FFFu + ((u >> 16) & 1u)) >> 16;   // RNE
  return (unsigned short)r;
}

// ---------------------------------------------------------------------------
// Kernel 0: convert all weights f32->bf16 and transpose to [N][K] (k-contig)
// so MFMA B-fragments are single 16B loads. Segments laid out back-to-back.
// ---------------------------------------------------------------------------
__global__ __launch_bounds__(256) void prep_weights(
    const float* __restrict__ wq, const float* __restrict__ fc1,
    const float* __restrict__ wk, const float* __restrict__ wv,
    const float* __restrict__ d2, const float* __restrict__ g1,
    const float* __restrict__ g2, const float* __restrict__ fc2,
    unsigned short* __restrict__ dst)
{
  long e = (long)blockIdx.x * 256 + threadIdx.x;
  if (e >= 425984) return;
  const float* src; int sh; int Nmat; long off;
  if (e < 32768)       { src = wq;  sh = 7; Nmat = 256; off = 0; }
  else if (e < 65536)  { src = fc1; sh = 7; Nmat = 256; off = 32768; }
  else if (e < 131072) { src = wk;  sh = 8; Nmat = 256; off = 65536; }
  else if (e < 196608) { src = wv;  sh = 8; Nmat = 256; off = 131072; }
  else if (e < 262144) { src = d2;  sh = 8; Nmat = 256; off = 196608; }
  else if (e < 327680) { src = g1;  sh = 8; Nmat = 256; off = 262144; }
  else if (e < 393216) { src = g2;  sh = 8; Nmat = 256; off = 327680; }
  else                 { src = fc2; sh = 8; Nmat = 128; off = 393216; }
  long d = e - off;
  int K = 1 << sh;
  int n = (int)(d >> sh), k = (int)(d & (K - 1));
  dst[e] = f2bf(src[(long)k * Nmat + n]);
}

// ---------------------------------------------------------------------------
// Kernel 1: exact KNN (unchanged from round 1 — known good).
// ---------------------------------------------------------------------------
__global__ __launch_bounds__(256) void knn_kernel(
    const float* __restrict__ xyz, const float* __restrict__ query,
    int* __restrict__ knn_out)
{
  __shared__ unsigned keys[NN];
  __shared__ unsigned long long red[4];
  const int tid = threadIdx.x;
  const int bm  = blockIdx.x;
  const int b   = bm >> 11;
  const float* q = query + (size_t)bm * QROW;
  const float qx = q[0], qy = q[1], qz = q[2];
  const float q2 = qx*qx + qy*qy + qz*qz;
  const float* X = xyz + (size_t)b * NN * 3;

  for (int n = tid; n < NN; n += 256) {
    float xx = X[3*n + 0], xy = X[3*n + 1], xz = X[3*n + 2];
    float x2 = xx*xx + xy*xy + xz*xz;
    float cr = qx*xx + qy*xy + qz*xz;
    float d  = q2 + x2 - 2.0f * cr;
    unsigned u = __float_as_uint(d);
    u = (u & 0x80000000u) ? ~u : (u | 0x80000000u);
    keys[n] = u;
  }
  __syncthreads();

  for (int r = 0; r < KK; ++r) {
    unsigned long long best = ~0ull;
    for (int n = tid; n < NN; n += 256) {
      unsigned long long cand = ((unsigned long long)keys[n] << 32) | (unsigned)n;
      best = cand < best ? cand : best;
    }
    #pragma unroll
    for (int d = 32; d >= 1; d >>= 1) {
      unsigned long long o = __shfl_xor(best, d, 64);
      best = o < best ? o : best;
    }
    if ((tid & 63) == 0) red[tid >> 6] = best;
    __syncthreads();
    if (tid == 0) {
      unsigned long long w01 = red[0] < red[1] ? red[0] : red[1];
      unsigned long long w23 = red[2] < red[3] ? red[2] : red[3];
      unsigned long long w   = w01 < w23 ? w01 : w23;
      unsigned n = (unsigned)(w & 0xffffffffu);
      keys[n] = 0xFFFFFFFFu;
      knn_out[bm*KK + r] = (int)n;
    }
    __syncthreads();
  }
}

// ---------------------------------------------------------------------------
// Balanced MFMA tile-GEMM helper: wave computes RT x 4 grid of 16x16 tiles.
// A-frags from LDS (row-major, stride in elems; stride*2 must be odd*16B),
// B-frags 16B direct from global bf16 W^T[N][K] (L2-resident).
// ---------------------------------------------------------------------------
template<int KT, int RT>
__device__ __forceinline__ void gemm_tiles(
    const unsigned short* aBase, int aStride,
    const unsigned short* __restrict__ bT,
    int lm, int lq, int colBase, int rtBase, floatx4 (&acc)[RT][4])
{
  #pragma unroll
  for (int ks = 0; ks < KT; ++ks) {
    short8 af[RT];
    #pragma unroll
    for (int rt = 0; rt < RT; ++rt)
      af[rt] = *(const short8*)&aBase[((rtBase + rt)*16 + lm)*aStride + ks*32 + lq*8];
    short8 bf[4];
    #pragma unroll
    for (int c = 0; c < 4; ++c)
      bf[c] = *(const short8*)&bT[(size_t)(colBase + c*16 + lm)*(KT*32) + ks*32 + lq*8];
    #pragma unroll
    for (int rt = 0; rt < RT; ++rt)
      #pragma unroll
      for (int c = 0; c < 4; ++c)
        acc[rt][c] = __builtin_amdgcn_mfma_f32_16x16x32_bf16(af[rt], bf[c], acc[rt][c], 0, 0, 0);
  }
}

// ---------------------------------------------------------------------------
// Kernel 2: fused block, MFMA version. 4 queries (64 rows) per 256-thread WG;
// wave w owns cols [64w,64w+64). C-layout: col=lane&15, row=(lane>>4)*4+reg.
// ---------------------------------------------------------------------------
__global__ __launch_bounds__(256, 2) void fused_mfma(
    const float* __restrict__ xyz, const float* __restrict__ features,
    const float* __restrict__ query,
    const float* __restrict__ fc1_b, const float* __restrict__ fc2_b,
    const float* __restrict__ d1_w,  const float* __restrict__ d1_b,
    const float* __restrict__ d2_b,
    const float* __restrict__ g1_b,  const float* __restrict__ g2_b,
    const unsigned short* __restrict__ wT,
    const int* __restrict__ knn_idx,
    float* __restrict__ out_res, float* __restrict__ out_attn)
{
  const unsigned short* wq_t  = wT;
  const unsigned short* fc1_t = wT + 32768;
  const unsigned short* wk_t  = wT + 65536;
  const unsigned short* wv_t  = wT + 131072;
  const unsigned short* d2_t  = wT + 196608;
  const unsigned short* g1_t  = wT + 262144;
  const unsigned short* g2_t  = wT + 327680;
  const unsigned short* fc2_t = wT + 393216;

  __shared__ alignas(16) unsigned short bufA[64*264];  // feat(136) / h1 / a / rm
  __shared__ alignas(16) unsigned short bufB[64*264];  // x / h
  __shared__ alignas(16) unsigned short s_qf[16*136];  // query_f bf16 (rows 0..3)
  __shared__ alignas(16) float s_q[4*256];             // q projection (f32)
  __shared__ float s_delta[64][4];
  __shared__ int   s_idx[64];

  const int tid = threadIdx.x;
  const int l  = tid & 63, w = tid >> 6;
  const int lm = l & 15,  lq = l >> 4;
  const int colBase = w * 64;
  const int bm0 = blockIdx.x << 2;
  const int b   = bm0 >> 11;

  // ---- Phase 0: indices, delta, query_f, feature gather ----
  if (tid < 64) {
    int q = tid >> 4, n = tid & 15;
    int idx = knn_idx[(bm0 + q)*KK + n];
    s_idx[tid] = idx;
    const float* qp = query + (size_t)(bm0 + q) * QROW;
    const float* xp = xyz + ((size_t)b*NN + idx)*3;
    s_delta[tid][0] = qp[0] - xp[0];
    s_delta[tid][1] = qp[1] - xp[1];
    s_delta[tid][2] = qp[2] - xp[2];
  }
  {
    int e = tid * 2;                    // 512 elems: rows 0..3 x 128 cols
    int q = e >> 7, c = e & 127;
    const float* qp = query + (size_t)(bm0 + q)*QROW + 3 + c;
    unsigned v = ((unsigned)f2bf(qp[1]) << 16) | f2bf(qp[0]);
    *(unsigned*)&s_qf[q*136 + c] = v;
  }
  __syncthreads();
  {
    int r = tid >> 2, c0 = (tid & 3) * 32;
    const float4* fp4 = (const float4*)(features + ((size_t)b*NN + s_idx[r])*DP + c0);
    unsigned short* dst = &bufA[r*136 + c0];
    #pragma unroll
    for (int i = 0; i < 8; ++i) {
      float4 v4 = fp4[i];
      *(unsigned*)&dst[i*4]     = ((unsigned)f2bf(v4.y) << 16) | f2bf(v4.x);
      *(unsigned*)&dst[i*4 + 2] = ((unsigned)f2bf(v4.w) << 16) | f2bf(v4.z);
    }
  }
  __syncthreads();

  const floatx4 zero4 = {0.f, 0.f, 0.f, 0.f};

  // ---- Phase 1: x = feat @ fc1 + b  -> bufB ;  q = qf @ wq -> s_q ----
  {
    floatx4 acc[4][4];
    #pragma unroll
    for (int rt = 0; rt < 4; ++rt)
      #pragma unroll
      for (int c = 0; c < 4; ++c) acc[rt][c] = zero4;
    gemm_tiles<4,4>(bufA, 136, fc1_t, lm, lq, colBase, 0, acc);
    #pragma unroll
    for (int c = 0; c < 4; ++c) {
      float bias = fc1_b[colBase + c*16 + lm];
      #pragma unroll
      for (int rt = 0; rt < 4; ++rt)
        #pragma unroll
        for (int r = 0; r < 4; ++r)
          bufB[(rt*16 + lq*4 + r)*264 + colBase + c*16 + lm] = f2bf(acc[rt][c][r] + bias);
    }
  }
  {
    floatx4 qa[1][4];
    #pragma unroll
    for (int c = 0; c < 4; ++c) qa[0][c] = zero4;
    gemm_tiles<4,1>(s_qf, 136, wq_t, lm, lq, colBase, 0, qa);
    if (lq == 0) {
      #pragma unroll
      for (int c = 0; c < 4; ++c)
        #pragma unroll
        for (int r = 0; r < 4; ++r)
          s_q[r*256 + colBase + c*16 + lm] = qa[0][c][r];   // row r == query r
    }
  }
  __syncthreads();   // x visible; bufA(feat) dead

  // ---- Phase 2: h1 = relu(delta @ d1 + b) -> bufA (VALU, tiny K=3) ----
  {
    int c = tid;
    float w0 = d1_w[c], w1 = d1_w[256 + c], w2 = d1_w[512 + c], bb = d1_b[c];
    #pragma unroll 4
    for (int r = 0; r < 64; ++r) {
      float v = fmaf(s_delta[r][2], w2, fmaf(s_delta[r][1], w1,
                fmaf(s_delta[r][0], w0, bb)));
      bufA[r*264 + c] = f2bf(v > 0.f ? v : 0.f);
    }
  }
  __syncthreads();   // h1 visible

  // ---- Phase 3: pe = h1 @ d2 + b (regs, persistent) ----
  floatx4 pe[4][4];
  #pragma unroll
  for (int rt = 0; rt < 4; ++rt)
    #pragma unroll
    for (int c = 0; c < 4; ++c) pe[rt][c] = zero4;
  gemm_tiles<8,4>(bufA, 264, d2_t, lm, lq, colBase, 0, pe);
  #pragma unroll
  for (int c = 0; c < 4; ++c) {
    float bias = d2_b[colBase + c*16 + lm];
    #pragma unroll
    for (int rt = 0; rt < 4; ++rt)
      #pragma unroll
      for (int r = 0; r < 4; ++r) pe[rt][c][r] += bias;
  }

  // ---- Phase 4: vpe = x @ wv + pe (regs, persistent) ----
  floatx4 vpe[4][4];
  #pragma unroll
  for (int rt = 0; rt < 4; ++rt)
    #pragma unroll
    for (int c = 0; c < 4; ++c) vpe[rt][c] = zero4;
  gemm_tiles<8,4>(bufB, 264, wv_t, lm, lq, colBase, 0, vpe);
  #pragma unroll
  for (int rt = 0; rt < 4; ++rt)
    #pragma unroll
    for (int c = 0; c < 4; ++c)
      #pragma unroll
      for (int r = 0; r < 4; ++r) vpe[rt][c][r] += pe[rt][c][r];
  __syncthreads();   // all waves done reading bufA(h1); a-writes may begin

  // ---- Phase 5: k = x @ wk ; a = q - k + pe -> bufA (rt-split for regs) ----
  #pragma unroll
  for (int half = 0; half < 2; ++half) {
    floatx4 kacc[2][4];
    #pragma unroll
    for (int rt = 0; rt < 2; ++rt)
      #pragma unroll
      for (int c = 0; c < 4; ++c) kacc[rt][c] = zero4;
    gemm_tiles<8,2>(bufB, 264, wk_t, lm, lq, colBase, half*2, kacc);
    #pragma unroll
    for (int rt2 = 0; rt2 < 2; ++rt2) {
      int rt = half*2 + rt2;
      #pragma unroll
      for (int c = 0; c < 4; ++c) {
        float qv = s_q[rt*256 + colBase + c*16 + lm];
        #pragma unroll
        for (int r = 0; r < 4; ++r) {
          float a = qv - kacc[rt2][c][r] + pe[rt][c][r];
          bufA[(rt*16 + lq*4 + r)*264 + colBase + c*16 + lm] = f2bf(a);
        }
      }
    }
  }
  __syncthreads();   // a visible; bufB(x) dead

  // ---- Phase 6: h = relu(a @ g1 + b) -> bufB ----
  {
    floatx4 h[4][4];
    #pragma unroll
    for (int rt = 0; rt < 4; ++rt)
      #pragma unroll
      for (int c = 0; c < 4; ++c) h[rt][c] = zero4;
    gemm_tiles<8,4>(bufA, 264, g1_t, lm, lq, colBase, 0, h);
    #pragma unroll
    for (int c = 0; c < 4; ++c) {
      float bias = g1_b[colBase + c*16 + lm];
      #pragma unroll
      for (int rt = 0; rt < 4; ++rt)
        #pragma unroll
        for (int r = 0; r < 4; ++r) {
          float v = h[rt][c][r] + bias;
          bufB[(rt*16 + lq*4 + r)*264 + colBase + c*16 + lm] = f2bf(v > 0.f ? v : 0.f);
        }
    }
  }
  __syncthreads();   // h visible; bufA(a) dead -> reuse as s_rm

  // ---- Phase 7/8: per-query logits = h @ g2 + b, softmax over neighbors,
  //      attn store, rm = sum_n attn * vpe ----
  unsigned short* s_rm = bufA;   // [16][264], rows 0..3 valid
  #pragma unroll
  for (int rt = 0; rt < 4; ++rt) {
    floatx4 lg[1][4];
    #pragma unroll
    for (int c = 0; c < 4; ++c) lg[0][c] = zero4;
    gemm_tiles<8,1>(bufB, 264, g2_t, lm, lq, colBase, rt, lg);
    #pragma unroll
    for (int c = 0; c < 4; ++c) {
      float bias = g2_b[colBase + c*16 + lm];
      float v[4];
      float mx = -INFINITY;
      #pragma unroll
      for (int r = 0; r < 4; ++r) {
        v[r] = (lg[0][c][r] + bias) * 0.0625f;
        mx = fmaxf(mx, v[r]);
      }
      mx = fmaxf(mx, __shfl_xor(mx, 16, 64));
      mx = fmaxf(mx, __shfl_xor(mx, 32, 64));
      float s = 0.f;
      #pragma unroll
      for (int r = 0; r < 4; ++r) { v[r] = __expf(v[r] - mx); s += v[r]; }
      s += __shfl_xor(s, 16, 64);
      s += __shfl_xor(s, 32, 64);
      float inv = 1.0f / s;
      float rm = 0.f;
      size_t abase = ((size_t)(bm0 + rt)*KK)*DM + colBase + c*16 + lm;
      #pragma unroll
      for (int r = 0; r < 4; ++r) {
        float at = v[r] * inv;
        out_attn[abase + (size_t)(lq*4 + r)*DM] = at;
        rm = fmaf(at, vpe[rt][c][r], rm);
      }
      rm += __shfl_xor(rm, 16, 64);
      rm += __shfl_xor(rm, 32, 64);
      if (lq == 0) s_rm[rt*264 + colBase + c*16 + lm] = f2bf(rm);
    }
  }
  __syncthreads();

  // ---- Phase 9: res = rm @ fc2 + b + query_f ----
  {
    floatx4 acc[2];
    acc[0] = zero4; acc[1] = zero4;
    #pragma unroll
    for (int ks = 0; ks < 8; ++ks) {
      short8 af = *(const short8*)&s_rm[lm*264 + ks*32 + lq*8];
      #pragma unroll
      for (int c = 0; c < 2; ++c) {
        int col = (w*2 + c)*16 + lm;
        short8 bf = *(const short8*)&fc2_t[(size_t)col*256 + ks*32 + lq*8];
        acc[c] = __builtin_amdgcn_mfma_f32_16x16x32_bf16(af, bf, acc[c], 0, 0, 0);
      }
    }
    if (lq == 0) {
      #pragma unroll
      for (int c = 0; c < 2; ++c) {
        int col = (w*2 + c)*16 + lm;
        float bias = fc2_b[col];
        #pragma unroll
        for (int r = 0; r < 4; ++r) {
          float res = acc[c][r] + bias + query[(size_t)(bm0 + r)*QROW + 3 + col];
          out_res[(size_t)(bm0 + r)*DP + col] = res;
        }
      }
    }
  }
}

extern "C" void kernel_launch(void* const* d_in, const int* in_sizes, int n_in,
                              void* d_out, int out_size, void* d_ws, size_t ws_size,
                              hipStream_t stream) {
  const float* xyz      = (const float*)d_in[0];
  const float* features = (const float*)d_in[1];
  const float* query    = (const float*)d_in[2];
  const float* fc1_w    = (const float*)d_in[3];
  const float* fc1_b    = (const float*)d_in[4];
  const float* fc2_w    = (const float*)d_in[5];
  const float* fc2_b    = (const float*)d_in[6];
  const float* d1_w     = (const float*)d_in[7];
  const float* d1_b     = (const float*)d_in[8];
  const float* d2_w     = (const float*)d_in[9];
  const float* d2_b     = (const float*)d_in[10];
  const float* g1_w     = (const float*)d_in[11];
  const float* g1_b     = (const float*)d_in[12];
  const float* g2_w     = (const float*)d_in[13];
  const float* g2_b     = (const float*)d_in[14];
  const float* wq       = (const float*)d_in[15];
  const float* wk       = (const float*)d_in[16];
  const float* wv       = (const float*)d_in[17];

  int* knn = (int*)d_ws;                                          // 512 KB
  unsigned short* wT = (unsigned short*)((char*)d_ws + 524288);   // 832 KB bf16
  float* out_res  = (float*)d_out;
  float* out_attn = (float*)d_out + (size_t)BB*MM*DP;

  prep_weights<<<1664, 256, 0, stream>>>(wq, fc1_w, wk, wv, d2_w, g1_w, g2_w, fc2_w, wT);
  knn_kernel<<<BB*MM, 256, 0, stream>>>(xyz, query, knn);
  fused_mfma<<<BB*MM/4, 256, 0, stream>>>(
      xyz, features, query, fc1_b, fc2_b, d1_w, d1_b, d2_b, g1_b, g2_b,
      wT, knn, out_res, out_attn);
}

// Round 3
// 714.500 us; speedup vs baseline: 2.9318x; 1.1725x over previous
//
#include <hip/hip_runtime.h>
#include <cstdint>
#include <cstddef>

#define BB 4
#define NN 8192
#define MM 2048
#define KK 16
#define DP 128
#define DM 256
#define QROW 131  // 3 + 128 floats per query row
#define CAP 512   // candidate buffer capacity for knn radix-select

typedef __attribute__((ext_vector_type(8))) short short8;
typedef __attribute__((ext_vector_type(4))) float floatx4;

__device__ __forceinline__ unsigned short f2bf(float x) {
  unsigned u = __float_as_uint(x);
  unsigned r = (u + 0x7FFFu + ((u >> 16) & 1u)) >> 16;   // RNE
  return (unsigned short)r;
}

// ---------------------------------------------------------------------------
// Kernel 0: convert all weights f32->bf16 and transpose to [N][K] (k-contig)
// so MFMA B-fragments are single 16B loads. Segments laid out back-to-back.
// ---------------------------------------------------------------------------
__global__ __launch_bounds__(256) void prep_weights(
    const float* __restrict__ wq, const float* __restrict__ fc1,
    const float* __restrict__ wk, const float* __restrict__ wv,
    const float* __restrict__ d2, const float* __restrict__ g1,
    const float* __restrict__ g2, const float* __restrict__ fc2,
    unsigned short* __restrict__ dst)
{
  long e = (long)blockIdx.x * 256 + threadIdx.x;
  if (e >= 425984) return;
  const float* src; int sh; int Nmat; long off;
  if (e < 32768)       { src = wq;  sh = 7; Nmat = 256; off = 0; }
  else if (e < 65536)  { src = fc1; sh = 7; Nmat = 256; off = 32768; }
  else if (e < 131072) { src = wk;  sh = 8; Nmat = 256; off = 65536; }
  else if (e < 196608) { src = wv;  sh = 8; Nmat = 256; off = 131072; }
  else if (e < 262144) { src = d2;  sh = 8; Nmat = 256; off = 196608; }
  else if (e < 327680) { src = g1;  sh = 8; Nmat = 256; off = 262144; }
  else if (e < 393216) { src = g2;  sh = 8; Nmat = 256; off = 327680; }
  else                 { src = fc2; sh = 8; Nmat = 128; off = 393216; }
  long d = e - off;
  int K = 1 << sh;
  int n = (int)(d >> sh), k = (int)(d & (K - 1));
  dst[e] = f2bf(src[(long)k * Nmat + n]);
}

// ---------------------------------------------------------------------------
// Kernel 1: exact KNN (k=16) via capped-histogram radix select.
// Pass A: distances -> sortable keys in LDS + capped 256-bin histogram of
// key>>24 (cap at 16 kills hot-bin atomic serialization; boundary-bin search
// is provably unchanged). Scan finds boundary bin B; compact bins<=B
// (superset of true top-16) into cand[]; wave 0 finishes with in-register
// argmin rounds (no barriers). Tie semantics identical to jax.lax.top_k.
// ---------------------------------------------------------------------------
__global__ __launch_bounds__(256) void knn_kernel(
    const float* __restrict__ xyz, const float* __restrict__ query,
    int* __restrict__ knn_out)
{
  __shared__ unsigned keys[NN];                 // 32 KB
  __shared__ unsigned long long cand[CAP];      // 4 KB
  __shared__ int hist[256];                     // 1 KB
  __shared__ int s_wsum[4];
  __shared__ int sB, s_cnt;

  const int tid = threadIdx.x;
  const int l   = tid & 63, w = tid >> 6;
  const int bm  = blockIdx.x;
  const int b   = bm >> 11;
  const float* q = query + (size_t)bm * QROW;
  const float qx = q[0], qy = q[1], qz = q[2];
  const float q2 = qx*qx + qy*qy + qz*qz;
  const float* X = xyz + (size_t)b * NN * 3;

  hist[tid] = 0;
  if (tid == 0) s_cnt = 0;
  __syncthreads();

  // ---- Pass A: keys + capped histogram ----
  for (int n = tid; n < NN; n += 256) {
    float xx = X[3*n + 0], xy = X[3*n + 1], xz = X[3*n + 2];
    float x2 = xx*xx + xy*xy + xz*xz;
    float cr = qx*xx + qy*xy + qz*xz;
    float d  = q2 + x2 - 2.0f * cr;
    unsigned u = __float_as_uint(d);
    u = (u & 0x80000000u) ? ~u : (u | 0x80000000u);  // ascending-sortable
    keys[n] = u;
    int bin = u >> 24;
    if (((volatile int*)hist)[bin] < 16) atomicAdd(&hist[bin], 1);
  }
  __syncthreads();

  // ---- Find boundary bin B: first bin with inclusive cumsum >= 16 ----
  {
    int h = hist[tid];
    int v = h;
    #pragma unroll
    for (int d = 1; d < 64; d <<= 1) {
      int o = __shfl_up(v, d, 64);
      if (l >= d) v += o;
    }
    if (l == 63) s_wsum[w] = v;
    __syncthreads();
    int off = 0;
    for (int i = 0; i < w; ++i) off += s_wsum[i];
    int incl = v + off;
    if (incl >= KK && incl - h < KK) sB = tid;   // unique
  }
  __syncthreads();

  // ---- Compact candidates: all keys with bin <= B ----
  {
    const unsigned limit = ((unsigned)(sB + 1)) << 24;  // sB<=255 -> <=2^32 ok via 64-bit? sB=255 => overflow
    const unsigned B = (unsigned)sB;
    for (int n = tid; n < NN; n += 256) {
      unsigned u = keys[n];
      if ((u >> 24) <= B) {
        int p = atomicAdd(&s_cnt, 1);
        if (p < CAP) cand[p] = ((unsigned long long)u << 32) | (unsigned)n;
      }
    }
    (void)limit;
  }
  __syncthreads();

  const int cnt = s_cnt;
  if (cnt <= CAP) {
    // ---- Fast path: wave 0 in-register selection, no barriers ----
    if (w == 0) {
      unsigned long long v[CAP/64];
      #pragma unroll
      for (int i = 0; i < CAP/64; ++i) {
        int p = i*64 + l;
        v[i] = (p < cnt) ? cand[p] : ~0ull;
      }
      for (int r = 0; r < KK; ++r) {
        unsigned long long m = v[0];
        #pragma unroll
        for (int i = 1; i < CAP/64; ++i) m = v[i] < m ? v[i] : m;
        #pragma unroll
        for (int d = 32; d >= 1; d >>= 1) {
          unsigned long long o = __shfl_xor(m, d, 64);
          m = o < m ? o : m;
        }
        if (l == 0) knn_out[bm*KK + r] = (int)(unsigned)(m & 0xffffffffu);
        #pragma unroll
        for (int i = 0; i < CAP/64; ++i) if (v[i] == m) v[i] = ~0ull;
      }
    }
  } else {
    // ---- Fallback: full 16-round scan over keys[] (keys intact) ----
    unsigned long long* red = cand;  // reuse as scratch
    for (int r = 0; r < KK; ++r) {
      unsigned long long best = ~0ull;
      for (int n = tid; n < NN; n += 256) {
        unsigned long long c = ((unsigned long long)keys[n] << 32) | (unsigned)n;
        best = c < best ? c : best;
      }
      #pragma unroll
      for (int d = 32; d >= 1; d >>= 1) {
        unsigned long long o = __shfl_xor(best, d, 64);
        best = o < best ? o : best;
      }
      if (l == 0) red[w] = best;
      __syncthreads();
      if (tid == 0) {
        unsigned long long w01 = red[0] < red[1] ? red[0] : red[1];
        unsigned long long w23 = red[2] < red[3] ? red[2] : red[3];
        unsigned long long ww  = w01 < w23 ? w01 : w23;
        unsigned n = (unsigned)(ww & 0xffffffffu);
        keys[n] = 0xFFFFFFFFu;
        knn_out[bm*KK + r] = (int)n;
      }
      __syncthreads();
    }
  }
}

// ---------------------------------------------------------------------------
// Balanced MFMA tile-GEMM helper: wave computes RT x 4 grid of 16x16 tiles.
// A-frags from LDS (row-major, stride in elems; stride*2 must be odd*16B),
// B-frags 16B direct from global bf16 W^T[N][K] (L2-resident).
// ---------------------------------------------------------------------------
template<int KT, int RT>
__device__ __forceinline__ void gemm_tiles(
    const unsigned short* aBase, int aStride,
    const unsigned short* __restrict__ bT,
    int lm, int lq, int colBase, int rtBase, floatx4 (&acc)[RT][4])
{
  #pragma unroll
  for (int ks = 0; ks < KT; ++ks) {
    short8 af[RT];
    #pragma unroll
    for (int rt = 0; rt < RT; ++rt)
      af[rt] = *(const short8*)&aBase[((rtBase + rt)*16 + lm)*aStride + ks*32 + lq*8];
    short8 bf[4];
    #pragma unroll
    for (int c = 0; c < 4; ++c)
      bf[c] = *(const short8*)&bT[(size_t)(colBase + c*16 + lm)*(KT*32) + ks*32 + lq*8];
    #pragma unroll
    for (int rt = 0; rt < RT; ++rt)
      #pragma unroll
      for (int c = 0; c < 4; ++c)
        acc[rt][c] = __builtin_amdgcn_mfma_f32_16x16x32_bf16(af[rt], bf[c], acc[rt][c], 0, 0, 0);
  }
}

// ---------------------------------------------------------------------------
// Kernel 2: fused block, MFMA version. 4 queries (64 rows) per 256-thread WG;
// wave w owns cols [64w,64w+64). C-layout: col=lane&15, row=(lane>>4)*4+reg.
// ---------------------------------------------------------------------------
__global__ __launch_bounds__(256, 2) void fused_mfma(
    const float* __restrict__ xyz, const float* __restrict__ features,
    const float* __restrict__ query,
    const float* __restrict__ fc1_b, const float* __restrict__ fc2_b,
    const float* __restrict__ d1_w,  const float* __restrict__ d1_b,
    const float* __restrict__ d2_b,
    const float* __restrict__ g1_b,  const float* __restrict__ g2_b,
    const unsigned short* __restrict__ wT,
    const int* __restrict__ knn_idx,
    float* __restrict__ out_res, float* __restrict__ out_attn)
{
  const unsigned short* wq_t  = wT;
  const unsigned short* fc1_t = wT + 32768;
  const unsigned short* wk_t  = wT + 65536;
  const unsigned short* wv_t  = wT + 131072;
  const unsigned short* d2_t  = wT + 196608;
  const unsigned short* g1_t  = wT + 262144;
  const unsigned short* g2_t  = wT + 327680;
  const unsigned short* fc2_t = wT + 393216;

  __shared__ alignas(16) unsigned short bufA[64*264];  // feat(136) / h1 / a / rm
  __shared__ alignas(16) unsigned short bufB[64*264];  // x / h
  __shared__ alignas(16) unsigned short s_qf[16*136];  // query_f bf16 (rows 0..3)
  __shared__ alignas(16) float s_q[4*256];             // q projection (f32)
  __shared__ float s_delta[64][4];
  __shared__ int   s_idx[64];

  const int tid = threadIdx.x;
  const int l  = tid & 63, w = tid >> 6;
  const int lm = l & 15,  lq = l >> 4;
  const int colBase = w * 64;
  const int bm0 = blockIdx.x << 2;
  const int b   = bm0 >> 11;

  // ---- Phase 0: indices, delta, query_f, feature gather ----
  if (tid < 64) {
    int q = tid >> 4, n = tid & 15;
    int idx = knn_idx[(bm0 + q)*KK + n];
    s_idx[tid] = idx;
    const float* qp = query + (size_t)(bm0 + q) * QROW;
    const float* xp = xyz + ((size_t)b*NN + idx)*3;
    s_delta[tid][0] = qp[0] - xp[0];
    s_delta[tid][1] = qp[1] - xp[1];
    s_delta[tid][2] = qp[2] - xp[2];
  }
  {
    int e = tid * 2;                    // 512 elems: rows 0..3 x 128 cols
    int q = e >> 7, c = e & 127;
    const float* qp = query + (size_t)(bm0 + q)*QROW + 3 + c;
    unsigned v = ((unsigned)f2bf(qp[1]) << 16) | f2bf(qp[0]);
    *(unsigned*)&s_qf[q*136 + c] = v;
  }
  __syncthreads();
  {
    int r = tid >> 2, c0 = (tid & 3) * 32;
    const float4* fp4 = (const float4*)(features + ((size_t)b*NN + s_idx[r])*DP + c0);
    unsigned short* dst = &bufA[r*136 + c0];
    #pragma unroll
    for (int i = 0; i < 8; ++i) {
      float4 v4 = fp4[i];
      *(unsigned*)&dst[i*4]     = ((unsigned)f2bf(v4.y) << 16) | f2bf(v4.x);
      *(unsigned*)&dst[i*4 + 2] = ((unsigned)f2bf(v4.w) << 16) | f2bf(v4.z);
    }
  }
  __syncthreads();

  const floatx4 zero4 = {0.f, 0.f, 0.f, 0.f};

  // ---- Phase 1: x = feat @ fc1 + b  -> bufB ;  q = qf @ wq -> s_q ----
  {
    floatx4 acc[4][4];
    #pragma unroll
    for (int rt = 0; rt < 4; ++rt)
      #pragma unroll
      for (int c = 0; c < 4; ++c) acc[rt][c] = zero4;
    gemm_tiles<4,4>(bufA, 136, fc1_t, lm, lq, colBase, 0, acc);
    #pragma unroll
    for (int c = 0; c < 4; ++c) {
      float bias = fc1_b[colBase + c*16 + lm];
      #pragma unroll
      for (int rt = 0; rt < 4; ++rt)
        #pragma unroll
        for (int r = 0; r < 4; ++r)
          bufB[(rt*16 + lq*4 + r)*264 + colBase + c*16 + lm] = f2bf(acc[rt][c][r] + bias);
    }
  }
  {
    floatx4 qa[1][4];
    #pragma unroll
    for (int c = 0; c < 4; ++c) qa[0][c] = zero4;
    gemm_tiles<4,1>(s_qf, 136, wq_t, lm, lq, colBase, 0, qa);
    if (lq == 0) {
      #pragma unroll
      for (int c = 0; c < 4; ++c)
        #pragma unroll
        for (int r = 0; r < 4; ++r)
          s_q[r*256 + colBase + c*16 + lm] = qa[0][c][r];   // row r == query r
    }
  }
  __syncthreads();   // x visible; bufA(feat) dead

  // ---- Phase 2: h1 = relu(delta @ d1 + b) -> bufA (VALU, tiny K=3) ----
  {
    int c = tid;
    float w0 = d1_w[c], w1 = d1_w[256 + c], w2 = d1_w[512 + c], bb = d1_b[c];
    #pragma unroll 4
    for (int r = 0; r < 64; ++r) {
      float v = fmaf(s_delta[r][2], w2, fmaf(s_delta[r][1], w1,
                fmaf(s_delta[r][0], w0, bb)));
      bufA[r*264 + c] = f2bf(v > 0.f ? v : 0.f);
    }
  }
  __syncthreads();   // h1 visible

  // ---- Phase 3: pe = h1 @ d2 + b (regs, persistent) ----
  floatx4 pe[4][4];
  #pragma unroll
  for (int rt = 0; rt < 4; ++rt)
    #pragma unroll
    for (int c = 0; c < 4; ++c) pe[rt][c] = zero4;
  gemm_tiles<8,4>(bufA, 264, d2_t, lm, lq, colBase, 0, pe);
  #pragma unroll
  for (int c = 0; c < 4; ++c) {
    float bias = d2_b[colBase + c*16 + lm];
    #pragma unroll
    for (int rt = 0; rt < 4; ++rt)
      #pragma unroll
      for (int r = 0; r < 4; ++r) pe[rt][c][r] += bias;
  }

  // ---- Phase 4: vpe = x @ wv + pe (regs, persistent) ----
  floatx4 vpe[4][4];
  #pragma unroll
  for (int rt = 0; rt < 4; ++rt)
    #pragma unroll
    for (int c = 0; c < 4; ++c) vpe[rt][c] = zero4;
  gemm_tiles<8,4>(bufB, 264, wv_t, lm, lq, colBase, 0, vpe);
  #pragma unroll
  for (int rt = 0; rt < 4; ++rt)
    #pragma unroll
    for (int c = 0; c < 4; ++c)
      #pragma unroll
      for (int r = 0; r < 4; ++r) vpe[rt][c][r] += pe[rt][c][r];
  __syncthreads();   // all waves done reading bufA(h1); a-writes may begin

  // ---- Phase 5: k = x @ wk ; a = q - k + pe -> bufA (rt-split for regs) ----
  #pragma unroll
  for (int half = 0; half < 2; ++half) {
    floatx4 kacc[2][4];
    #pragma unroll
    for (int rt = 0; rt < 2; ++rt)
      #pragma unroll
      for (int c = 0; c < 4; ++c) kacc[rt][c] = zero4;
    gemm_tiles<8,2>(bufB, 264, wk_t, lm, lq, colBase, half*2, kacc);
    #pragma unroll
    for (int rt2 = 0; rt2 < 2; ++rt2) {
      int rt = half*2 + rt2;
      #pragma unroll
      for (int c = 0; c < 4; ++c) {
        float qv = s_q[rt*256 + colBase + c*16 + lm];
        #pragma unroll
        for (int r = 0; r < 4; ++r) {
          float a = qv - kacc[rt2][c][r] + pe[rt][c][r];
          bufA[(rt*16 + lq*4 + r)*264 + colBase + c*16 + lm] = f2bf(a);
        }
      }
    }
  }
  __syncthreads();   // a visible; bufB(x) dead

  // ---- Phase 6: h = relu(a @ g1 + b) -> bufB ----
  {
    floatx4 h[4][4];
    #pragma unroll
    for (int rt = 0; rt < 4; ++rt)
      #pragma unroll
      for (int c = 0; c < 4; ++c) h[rt][c] = zero4;
    gemm_tiles<8,4>(bufA, 264, g1_t, lm, lq, colBase, 0, h);
    #pragma unroll
    for (int c = 0; c < 4; ++c) {
      float bias = g1_b[colBase + c*16 + lm];
      #pragma unroll
      for (int rt = 0; rt < 4; ++rt)
        #pragma unroll
        for (int r = 0; r < 4; ++r) {
          float v = h[rt][c][r] + bias;
          bufB[(rt*16 + lq*4 + r)*264 + colBase + c*16 + lm] = f2bf(v > 0.f ? v : 0.f);
        }
    }
  }
  __syncthreads();   // h visible; bufA(a) dead -> reuse as s_rm

  // ---- Phase 7/8: per-query logits = h @ g2 + b, softmax over neighbors,
  //      attn store, rm = sum_n attn * vpe ----
  unsigned short* s_rm = bufA;   // [16][264], rows 0..3 valid
  #pragma unroll
  for (int rt = 0; rt < 4; ++rt) {
    floatx4 lg[1][4];
    #pragma unroll
    for (int c = 0; c < 4; ++c) lg[0][c] = zero4;
    gemm_tiles<8,1>(bufB, 264, g2_t, lm, lq, colBase, rt, lg);
    #pragma unroll
    for (int c = 0; c < 4; ++c) {
      float bias = g2_b[colBase + c*16 + lm];
      float v[4];
      float mx = -INFINITY;
      #pragma unroll
      for (int r = 0; r < 4; ++r) {
        v[r] = (lg[0][c][r] + bias) * 0.0625f;
        mx = fmaxf(mx, v[r]);
      }
      mx = fmaxf(mx, __shfl_xor(mx, 16, 64));
      mx = fmaxf(mx, __shfl_xor(mx, 32, 64));
      float s = 0.f;
      #pragma unroll
      for (int r = 0; r < 4; ++r) { v[r] = __expf(v[r] - mx); s += v[r]; }
      s += __shfl_xor(s, 16, 64);
      s += __shfl_xor(s, 32, 64);
      float inv = 1.0f / s;
      float rm = 0.f;
      size_t abase = ((size_t)(bm0 + rt)*KK)*DM + colBase + c*16 + lm;
      #pragma unroll
      for (int r = 0; r < 4; ++r) {
        float at = v[r] * inv;
        out_attn[abase + (size_t)(lq*4 + r)*DM] = at;
        rm = fmaf(at, vpe[rt][c][r], rm);
      }
      rm += __shfl_xor(rm, 16, 64);
      rm += __shfl_xor(rm, 32, 64);
      if (lq == 0) s_rm[rt*264 + colBase + c*16 + lm] = f2bf(rm);
    }
  }
  __syncthreads();

  // ---- Phase 9: res = rm @ fc2 + b + query_f ----
  {
    floatx4 acc[2];
    acc[0] = zero4; acc[1] = zero4;
    #pragma unroll
    for (int ks = 0; ks < 8; ++ks) {
      short8 af = *(const short8*)&s_rm[lm*264 + ks*32 + lq*8];
      #pragma unroll
      for (int c = 0; c < 2; ++c) {
        int col = (w*2 + c)*16 + lm;
        short8 bf = *(const short8*)&fc2_t[(size_t)col*256 + ks*32 + lq*8];
        acc[c] = __builtin_amdgcn_mfma_f32_16x16x32_bf16(af, bf, acc[c], 0, 0, 0);
      }
    }
    if (lq == 0) {
      #pragma unroll
      for (int c = 0; c < 2; ++c) {
        int col = (w*2 + c)*16 + lm;
        float bias = fc2_b[col];
        #pragma unroll
        for (int r = 0; r < 4; ++r) {
          float res = acc[c][r] + bias + query[(size_t)(bm0 + r)*QROW + 3 + col];
          out_res[(size_t)(bm0 + r)*DP + col] = res;
        }
      }
    }
  }
}

extern "C" void kernel_launch(void* const* d_in, const int* in_sizes, int n_in,
                              void* d_out, int out_size, void* d_ws, size_t ws_size,
                              hipStream_t stream) {
  const float* xyz      = (const float*)d_in[0];
  const float* features = (const float*)d_in[1];
  const float* query    = (const float*)d_in[2];
  const float* fc1_w    = (const float*)d_in[3];
  const float* fc1_b    = (const float*)d_in[4];
  const float* fc2_w    = (const float*)d_in[5];
  const float* fc2_b    = (const float*)d_in[6];
  const float* d1_w     = (const float*)d_in[7];
  const float* d1_b     = (const float*)d_in[8];
  const float* d2_w     = (const float*)d_in[9];
  const float* d2_b     = (const float*)d_in[10];
  const float* g1_w     = (const float*)d_in[11];
  const float* g1_b     = (const float*)d_in[12];
  const float* g2_w     = (const float*)d_in[13];
  const float* g2_b     = (const float*)d_in[14];
  const float* wq       = (const float*)d_in[15];
  const float* wk       = (const float*)d_in[16];
  const float* wv       = (const float*)d_in[17];

  int* knn = (int*)d_ws;                                          // 512 KB
  unsigned short* wT = (unsigned short*)((char*)d_ws + 524288);   // 832 KB bf16
  float* out_res  = (float*)d_out;
  float* out_attn = (float*)d_out + (size_t)BB*MM*DP;

  prep_weights<<<1664, 256, 0, stream>>>(wq, fc1_w, wk, wv, d2_w, g1_w, g2_w, fc2_w, wT);
  knn_kernel<<<BB*MM, 256, 0, stream>>>(xyz, query, knn);
  fused_mfma<<<BB*MM/4, 256, 0, stream>>>(
      xyz, features, query, fc1_b, fc2_b, d1_w, d1_b, d2_b, g1_b, g2_b,
      wT, knn, out_res, out_attn);
}